// Round 1
// baseline (300.556 us; speedup 1.0000x reference)
//
#include <hip/hip_runtime.h>

// Problem constants
#define BB   8
#define CC   128
#define HH   96
#define WW2  96
#define LL   9216          // H*W
#define EPSF 1e-5f

__device__ __forceinline__ float silu_f(float x) {
    return x / (1.0f + __expf(-x));
}

// ---------------------------------------------------------------------------
// Kernel A: UV = W_in @ x  (per batch, channel-major). U=silu(uv[0:128]),
// V=uv[128:256] raw. x:(B,128,L) row-major over L.  grid(144, B), block 256.
// ---------------------------------------------------------------------------
__global__ __launch_bounds__(256) void k_uv(const float* __restrict__ x,
        const float* __restrict__ W_in, const float* __restrict__ b_in,
        float* __restrict__ U, float* __restrict__ V) {
    __shared__ float xt[128][64];
    const int b   = blockIdx.y;
    const int l0  = blockIdx.x * 64;
    const int tid = threadIdx.x;
    const int lane = tid & 63;

    // stage x tile: 128 channels x 64 positions (coalesced 64-wide rows)
    for (int k = 0; k < 32; ++k) {
        int idx = tid + k * 256;
        int c = idx >> 6, col = idx & 63;
        xt[c][col] = x[((size_t)(b * 128 + c)) * LL + l0 + col];
    }
    __syncthreads();

    const int wv = __builtin_amdgcn_readfirstlane(tid >> 6); // wave id 0..3
    const int o0 = wv * 64;                                  // 64 outputs/wave

    for (int ch = 0; ch < 4; ++ch) {
        const int ob = o0 + ch * 16;
        float acc[16];
        #pragma unroll
        for (int r = 0; r < 16; ++r) acc[r] = b_in[ob + r];
        #pragma unroll 4
        for (int c = 0; c < 128; ++c) {
            float xv = xt[c][lane];
            #pragma unroll
            for (int r = 0; r < 16; ++r)
                acc[r] = fmaf(W_in[(ob + r) * 128 + c], xv, acc[r]);
        }
        #pragma unroll
        for (int r = 0; r < 16; ++r) {
            int o = ob + r;
            if (o < 128) {
                U[((size_t)(b * 128 + o)) * LL + l0 + lane] = silu_f(acc[r]);
            } else {
                V[((size_t)(b * 128 + (o - 128))) * LL + l0 + lane] = acc[r];
            }
        }
    }
}

// ---------------------------------------------------------------------------
// Kernel B: fused 4-direction depthwise conv + SiLU gate + LayerNorm + sum.
// For each token, all 4 directions (lr, rl, tb, bt) are computed via flat-
// sequence neighbor offsets (reversed dirs = flipped conv kernel).
// Writes ysum = 0.25 * sum_dirs LN(y_dir), channel-major.
// grid(3, 96, B)  block 256 = 32 tokens x 8 channel-groups(16 ch each).
// NOTE: U and ysum may alias (same buffer) -> neither is __restrict__.
// ---------------------------------------------------------------------------
__global__ __launch_bounds__(256) void k_mixer(const float* U,
        const float* __restrict__ V, const float* __restrict__ dw_w,
        const float* __restrict__ dw_b, const float* __restrict__ gamma,
        const float* __restrict__ beta, float* ysum) {
    const int b   = blockIdx.z;
    const int h   = blockIdx.y;
    const int w0  = blockIdx.x * 32;
    const int tid = threadIdx.x;
    const int tok = tid & 31;
    const int cg  = tid >> 5;          // 0..7
    const int w   = w0 + tok;
    const int m   = h * WW2 + w;       // row-major flat index

    // precompute 7 tap offsets for horizontal (flat row-major) and vertical
    // (flat col-major) sequence orders; -1 == zero pad
    int offH[7], offV[7];
    #pragma unroll
    for (int j = 0; j < 7; ++j) {
        int d  = j - 3;
        int mm = m + d;
        offH[j] = (mm >= 0 && mm < LL) ? mm : -1;
        int q = w * HH + h + d;        // col-major flat index + d
        if (q >= 0 && q < LL) {
            int h2 = q % HH, w2 = q / HH;
            offV[j] = h2 * WW2 + w2;
        } else offV[j] = -1;
    }

    __shared__ float red[4][8][32];
    const size_t baseb = (size_t)b * 128 * LL;

    float ysr[16];
    #pragma unroll
    for (int i = 0; i < 16; ++i) ysr[i] = 0.0f;

    auto do_pair = [&](const int* off) {
        float ya[16], yb[16];
        float sa = 0.f, qa = 0.f, sb = 0.f, qb = 0.f;
        #pragma unroll
        for (int i = 0; i < 16; ++i) {
            int c = cg * 16 + i;
            const float* vb = V + baseb + (size_t)c * LL;
            float t[7];
            #pragma unroll
            for (int j = 0; j < 7; ++j) t[j] = (off[j] >= 0) ? vb[off[j]] : 0.0f;
            float ca = dw_b[c], cb = dw_b[c];
            #pragma unroll
            for (int j = 0; j < 7; ++j) {
                float wj = dw_w[c * 7 + j];
                ca = fmaf(wj, t[j],     ca);   // forward kernel
                cb = fmaf(wj, t[6 - j], cb);   // flipped kernel (reversed dir)
            }
            float u  = U[baseb + (size_t)c * LL + m];
            float va = u * silu_f(ca);
            float vv = u * silu_f(cb);
            ya[i] = va; yb[i] = vv;
            sa += va; qa += va * va; sb += vv; qb += vv * vv;
        }
        red[0][cg][tok] = sa; red[1][cg][tok] = qa;
        red[2][cg][tok] = sb; red[3][cg][tok] = qb;
        __syncthreads();
        float Sa = 0.f, Qa = 0.f, Sb = 0.f, Qb = 0.f;
        #pragma unroll
        for (int g = 0; g < 8; ++g) {
            Sa += red[0][g][tok]; Qa += red[1][g][tok];
            Sb += red[2][g][tok]; Qb += red[3][g][tok];
        }
        const float inv = 1.0f / 128.0f;
        float mua = Sa * inv, vara = Qa * inv - mua * mua;
        float mub = Sb * inv, varb = Qb * inv - mub * mub;
        float ra = rsqrtf(vara + EPSF);
        float rb = rsqrtf(varb + EPSF);
        #pragma unroll
        for (int i = 0; i < 16; ++i) {
            int c = cg * 16 + i;
            float g = gamma[c], be = beta[c];
            ysr[i] += (ya[i] - mua) * ra * g + be
                    + (yb[i] - mub) * rb * g + be;
        }
        __syncthreads();   // red reused by next pair
    };

    do_pair(offH);   // lr + rl
    do_pair(offV);   // tb + bt

    #pragma unroll
    for (int i = 0; i < 16; ++i) {
        int c = cg * 16 + i;
        ysum[baseb + (size_t)c * LL + m] = 0.25f * ysr[i];
    }
}

// ---------------------------------------------------------------------------
// Kernel C: out = W_out @ ysum + b_out  (ysum already scaled by 0.25)
// grid(144, B), block 256.
// ---------------------------------------------------------------------------
__global__ __launch_bounds__(256) void k_out(const float* __restrict__ ysum,
        const float* __restrict__ W_out, const float* __restrict__ b_out,
        float* __restrict__ out) {
    __shared__ float yt[128][64];
    const int b   = blockIdx.y;
    const int l0  = blockIdx.x * 64;
    const int tid = threadIdx.x;
    const int lane = tid & 63;

    for (int k = 0; k < 32; ++k) {
        int idx = tid + k * 256;
        int c = idx >> 6, col = idx & 63;
        yt[c][col] = ysum[((size_t)(b * 128 + c)) * LL + l0 + col];
    }
    __syncthreads();

    const int wv = __builtin_amdgcn_readfirstlane(tid >> 6);
    const int o0 = wv * 32;   // 32 outputs per wave

    for (int ch = 0; ch < 2; ++ch) {
        const int ob = o0 + ch * 16;
        float acc[16];
        #pragma unroll
        for (int r = 0; r < 16; ++r) acc[r] = b_out[ob + r];
        #pragma unroll 4
        for (int c = 0; c < 128; ++c) {
            float xv = yt[c][lane];
            #pragma unroll
            for (int r = 0; r < 16; ++r)
                acc[r] = fmaf(W_out[(ob + r) * 128 + c], xv, acc[r]);
        }
        #pragma unroll
        for (int r = 0; r < 16; ++r)
            out[((size_t)(b * 128 + ob + r)) * LL + l0 + lane] = acc[r];
    }
}

// ---------------------------------------------------------------------------
extern "C" void kernel_launch(void* const* d_in, const int* in_sizes, int n_in,
                              void* d_out, int out_size, void* d_ws, size_t ws_size,
                              hipStream_t stream) {
    const float* x     = (const float*)d_in[0];
    const float* W_in  = (const float*)d_in[1];
    const float* b_in  = (const float*)d_in[2];
    const float* dw_w  = (const float*)d_in[3];
    const float* dw_b  = (const float*)d_in[4];
    const float* gamma = (const float*)d_in[5];
    const float* beta  = (const float*)d_in[6];
    const float* W_out = (const float*)d_in[7];
    const float* b_out = (const float*)d_in[8];
    float* out = (float*)d_out;

    // workspace: U (B,128,L) fp32 then V (B,128,L) fp32 = 75,497,472 bytes.
    // ysum reuses U's buffer (each k_mixer block only writes its own tokens
    // after its last read of them; kernel boundary flushes caches for k_out).
    float* U = (float*)d_ws;
    float* V = U + (size_t)BB * CC * LL;
    float* ysum = U;

    dim3 gA(LL / 64, BB);
    k_uv<<<gA, 256, 0, stream>>>(x, W_in, b_in, U, V);

    dim3 gB(3, HH, BB);
    k_mixer<<<gB, 256, 0, stream>>>(U, V, dw_w, dw_b, gamma, beta, ysum);

    dim3 gC(LL / 64, BB);
    k_out<<<gC, 256, 0, stream>>>(ysum, W_out, b_out, out);
}

// Round 2
// 130.183 us; speedup vs baseline: 2.3087x; 2.3087x over previous
//
#include <hip/hip_runtime.h>

#define BB 8
#define CC 128
#define HH 96
#define WW 96
#define LL 9216
#define EPSF 1e-5f

typedef __attribute__((ext_vector_type(8))) short short8;
typedef __attribute__((ext_vector_type(4))) float f32x4;
typedef __attribute__((ext_vector_type(4))) unsigned int uint32x4;
typedef unsigned short ushort_t;
typedef unsigned int uint32;

__device__ __forceinline__ float silu_f(float x){ return x / (1.0f + __expf(-x)); }
__device__ __forceinline__ ushort_t f2bf(float f){
    uint32 u = __float_as_uint(f);
    u += 0x7FFFu + ((u >> 16) & 1u);          // RNE
    return (ushort_t)(u >> 16);
}
__device__ __forceinline__ float bf2f(ushort_t h){ return __uint_as_float(((uint32)h) << 16); }
__device__ __forceinline__ uint32 pack2(float a, float b){
    return (uint32)f2bf(a) | ((uint32)f2bf(b) << 16);
}

// ---------------------------------------------------------------------------
// Convert W_in (256x128) and W_out (128x128) fp32 -> bf16. grid 128 x 256.
// ---------------------------------------------------------------------------
__global__ void k_prep(const float* __restrict__ Win, const float* __restrict__ Wout,
                       ushort_t* __restrict__ WinB, ushort_t* __restrict__ WoutB){
    int i = blockIdx.x * 256 + threadIdx.x;
    if (i < 256 * 128) WinB[i] = f2bf(Win[i]);
    if (i < 128 * 128) WoutB[i] = f2bf(Wout[i]);
}

// ---------------------------------------------------------------------------
// Transpose+convert x (B,128,L) fp32 -> xT (B,L,128) bf16. grid(144,B) x 256.
// ---------------------------------------------------------------------------
__global__ __launch_bounds__(256) void k_xpose(const float* __restrict__ x,
                                               ushort_t* __restrict__ xT){
    __shared__ float xt[128][65];
    const int b = blockIdx.y, l0 = blockIdx.x * 64, tid = threadIdx.x;
    const int col = tid & 63;
    #pragma unroll
    for (int k = 0; k < 32; ++k){
        int c = (tid >> 6) + k * 4;
        xt[c][col] = x[((size_t)(b * 128 + c)) * LL + l0 + col];
    }
    __syncthreads();
    const int lane = tid & 63;
    uint32* outbase = (uint32*)(xT + (size_t)b * LL * 128);
    #pragma unroll
    for (int p = 0; p < 16; ++p){
        int l = (tid >> 6) + p * 4;
        uint32 v = pack2(xt[2 * lane][l], xt[2 * lane + 1][l]);
        outbase[(size_t)(l0 + l) * 64 + lane] = v;
    }
}

// ---------------------------------------------------------------------------
// GEMM A: uv[o,l] = sum_c W_in[o,c] * x[c,l]; U = silu(uv[0:128]) bf16,
// V = uv[128:256] bf16, both token-major (B,L,128).
// block 256 = 4 waves; wave w owns o-range [64w, 64w+64); tile 64 l.
// ---------------------------------------------------------------------------
__global__ __launch_bounds__(256) void k_gemmA(const ushort_t* __restrict__ xT,
        const ushort_t* __restrict__ WinB, const float* __restrict__ b_in,
        ushort_t* __restrict__ U, ushort_t* __restrict__ V){
    __shared__ ushort_t eb[4][64][72];
    const int b = blockIdx.y, l0 = blockIdx.x * 64, tid = threadIdx.x;
    const int wv = tid >> 6, lane = tid & 63;
    const int lo = lane & 15, hi = lane >> 4;
    const int o0 = wv * 64;
    const ushort_t* xb = xT + (size_t)b * LL * 128;

    const f32x4 zero = {0.f, 0.f, 0.f, 0.f};
    f32x4 acc[4][4];
    #pragma unroll
    for (int om = 0; om < 4; ++om)
        #pragma unroll
        for (int lf = 0; lf < 4; ++lf) acc[om][lf] = zero;

    #pragma unroll
    for (int ks = 0; ks < 4; ++ks){
        short8 af[4], bfr[4];
        #pragma unroll
        for (int om = 0; om < 4; ++om)
            af[om] = *(const short8*)(WinB + (size_t)(o0 + om * 16 + lo) * 128 + ks * 32 + hi * 8);
        #pragma unroll
        for (int lf = 0; lf < 4; ++lf)
            bfr[lf] = *(const short8*)(xb + (size_t)(l0 + lf * 16 + lo) * 128 + ks * 32 + hi * 8);
        #pragma unroll
        for (int om = 0; om < 4; ++om)
            #pragma unroll
            for (int lf = 0; lf < 4; ++lf)
                acc[om][lf] = __builtin_amdgcn_mfma_f32_16x16x32_bf16(af[om], bfr[lf], acc[om][lf], 0, 0, 0);
    }

    const bool isU = (wv < 2);
    #pragma unroll
    for (int om = 0; om < 4; ++om){
        int ob = o0 + om * 16 + hi * 4;
        f32x4 bia = *(const f32x4*)(b_in + ob);
        #pragma unroll
        for (int lf = 0; lf < 4; ++lf){
            f32x4 v = acc[om][lf];
            float v0 = v[0] + bia[0], v1 = v[1] + bia[1];
            float v2 = v[2] + bia[2], v3 = v[3] + bia[3];
            if (isU){ v0 = silu_f(v0); v1 = silu_f(v1); v2 = silu_f(v2); v3 = silu_f(v3); }
            int ll = lf * 16 + lo;
            uint32* row = (uint32*)(&eb[wv][ll][0]);
            row[om * 8 + hi * 2    ] = pack2(v0, v1);
            row[om * 8 + hi * 2 + 1] = pack2(v2, v3);
        }
    }
    __syncthreads();

    uint32* Ub = (uint32*)(U + (size_t)b * LL * 128);
    uint32* Vb = (uint32*)(V + (size_t)b * LL * 128);
    const int wsrc = lane >> 5, jcol = lane & 31;
    #pragma unroll
    for (int p = 0; p < 16; ++p){
        int l = (tid >> 6) + p * 4;
        uint32 vu = ((uint32*)&eb[0 + wsrc][l][0])[jcol];
        uint32 vv = ((uint32*)&eb[2 + wsrc][l][0])[jcol];
        Ub[(size_t)(l0 + l) * 64 + lane] = vu;
        Vb[(size_t)(l0 + l) * 64 + lane] = vv;
    }
}

// ---------------------------------------------------------------------------
// Mixer: 4-direction depthwise conv + SiLU gate + LayerNorm, summed, *0.25.
// Token-major bf16 in/out. ysum aliases U (each thread writes only its own
// token, after reading it). grid(3, 96, B) x 256 (32 tok x 8 cgroups).
// ---------------------------------------------------------------------------
__global__ __launch_bounds__(256) void k_mixer(const ushort_t* U,
        const ushort_t* __restrict__ V, const float* __restrict__ dw_w,
        const float* __restrict__ dw_b, const float* __restrict__ gamma,
        const float* __restrict__ beta, ushort_t* ysum){
    __shared__ float red[4][8][32];
    __shared__ float wsm[128 * 7], bsm[128], gsm[128], besm[128];
    const int b = blockIdx.z, h = blockIdx.y, w0 = blockIdx.x * 32;
    const int tid = threadIdx.x, tok = tid & 31, cg = tid >> 5;
    const int w = w0 + tok, m = h * WW + w;

    for (int i = tid; i < 128 * 7; i += 256) wsm[i] = dw_w[i];
    if (tid < 128){ bsm[tid] = dw_b[tid]; gsm[tid] = gamma[tid]; besm[tid] = beta[tid]; }
    __syncthreads();

    int offH[7], offV[7];
    #pragma unroll
    for (int j = 0; j < 7; ++j){
        int d = j - 3;
        int mm = m + d;
        offH[j] = (mm >= 0 && mm < LL) ? mm : -1;
        int q = w * HH + h + d;
        offV[j] = (q >= 0 && q < LL) ? ((q % HH) * WW + q / HH) : -1;
    }

    const size_t base = (size_t)b * LL * 128;
    const ushort_t* Vb = V + base;

    float uf[16];
    {
        short8 u0 = *(const short8*)(U + base + (size_t)m * 128 + cg * 16);
        short8 u1 = *(const short8*)(U + base + (size_t)m * 128 + cg * 16 + 8);
        #pragma unroll
        for (int i = 0; i < 8; ++i){
            uf[i]     = bf2f((ushort_t)u0[i]);
            uf[8 + i] = bf2f((ushort_t)u1[i]);
        }
    }

    float ysr[16];
    #pragma unroll
    for (int i = 0; i < 16; ++i) ysr[i] = 0.f;

    auto do_pair = [&](const int* off){
        short8 t0[7], t1[7];
        #pragma unroll
        for (int j = 0; j < 7; ++j){
            if (off[j] >= 0){
                t0[j] = *(const short8*)(Vb + (size_t)off[j] * 128 + cg * 16);
                t1[j] = *(const short8*)(Vb + (size_t)off[j] * 128 + cg * 16 + 8);
            } else {
                short8 z = {0,0,0,0,0,0,0,0};
                t0[j] = z; t1[j] = z;
            }
        }
        float ya[16], yb[16];
        float sa = 0.f, qa = 0.f, sb = 0.f, qb = 0.f;
        #pragma unroll
        for (int i = 0; i < 16; ++i){
            int c = cg * 16 + i;
            float ca = bsm[c], cb = ca;
            #pragma unroll
            for (int j = 0; j < 7; ++j){
                float tv = (i < 8) ? bf2f((ushort_t)t0[j][i]) : bf2f((ushort_t)t1[j][i - 8]);
                ca = fmaf(wsm[c * 7 + j],     tv, ca);
                cb = fmaf(wsm[c * 7 + 6 - j], tv, cb);
            }
            float va  = uf[i] * silu_f(ca);
            float vb2 = uf[i] * silu_f(cb);
            ya[i] = va; yb[i] = vb2;
            sa += va; qa += va * va; sb += vb2; qb += vb2 * vb2;
        }
        red[0][cg][tok] = sa; red[1][cg][tok] = qa;
        red[2][cg][tok] = sb; red[3][cg][tok] = qb;
        __syncthreads();
        float Sa = 0.f, Qa = 0.f, Sb = 0.f, Qb = 0.f;
        #pragma unroll
        for (int g = 0; g < 8; ++g){
            Sa += red[0][g][tok]; Qa += red[1][g][tok];
            Sb += red[2][g][tok]; Qb += red[3][g][tok];
        }
        const float inv = 1.f / 128.f;
        float mua = Sa * inv, vara = Qa * inv - mua * mua;
        float mub = Sb * inv, varb = Qb * inv - mub * mub;
        float ra = rsqrtf(vara + EPSF), rb = rsqrtf(varb + EPSF);
        #pragma unroll
        for (int i = 0; i < 16; ++i){
            int c = cg * 16 + i;
            float g = gsm[c], be = besm[c];
            ysr[i] += (ya[i] - mua) * ra * g + be + (yb[i] - mub) * rb * g + be;
        }
        __syncthreads();
    };

    do_pair(offH);
    do_pair(offV);

    uint32 pk[8];
    #pragma unroll
    for (int i = 0; i < 8; ++i) pk[i] = pack2(0.25f * ysr[2 * i], 0.25f * ysr[2 * i + 1]);
    uint32* orow = (uint32*)(ysum + base + (size_t)m * 128 + cg * 16);
    uint32x4 s0 = {pk[0], pk[1], pk[2], pk[3]};
    uint32x4 s1 = {pk[4], pk[5], pk[6], pk[7]};
    *(uint32x4*)(orow)     = s0;
    *(uint32x4*)(orow + 4) = s1;
}

// ---------------------------------------------------------------------------
// GEMM C: out[o,l] = sum_c W_out[o,c] * ysum[l,c] + b_out[o], fp32 out
// channel-major (B,128,L). block 256 = 4 waves; wave owns 32-o chunk.
// ---------------------------------------------------------------------------
__global__ __launch_bounds__(256) void k_gemmC(const ushort_t* __restrict__ ysum,
        const ushort_t* __restrict__ WoutB, const float* __restrict__ b_out,
        float* __restrict__ out){
    __shared__ float ec[4][32][65];
    const int b = blockIdx.y, l0 = blockIdx.x * 64, tid = threadIdx.x;
    const int wv = tid >> 6, lane = tid & 63;
    const int lo = lane & 15, hi = lane >> 4;
    const int o0 = wv * 32;
    const ushort_t* yb = ysum + (size_t)b * LL * 128;

    const f32x4 zero = {0.f, 0.f, 0.f, 0.f};
    f32x4 acc[2][4];
    #pragma unroll
    for (int om = 0; om < 2; ++om)
        #pragma unroll
        for (int lf = 0; lf < 4; ++lf) acc[om][lf] = zero;

    #pragma unroll
    for (int ks = 0; ks < 4; ++ks){
        short8 af[2], bfr[4];
        #pragma unroll
        for (int om = 0; om < 2; ++om)
            af[om] = *(const short8*)(WoutB + (size_t)(o0 + om * 16 + lo) * 128 + ks * 32 + hi * 8);
        #pragma unroll
        for (int lf = 0; lf < 4; ++lf)
            bfr[lf] = *(const short8*)(yb + (size_t)(l0 + lf * 16 + lo) * 128 + ks * 32 + hi * 8);
        #pragma unroll
        for (int om = 0; om < 2; ++om)
            #pragma unroll
            for (int lf = 0; lf < 4; ++lf)
                acc[om][lf] = __builtin_amdgcn_mfma_f32_16x16x32_bf16(af[om], bfr[lf], acc[om][lf], 0, 0, 0);
    }

    #pragma unroll
    for (int om = 0; om < 2; ++om){
        #pragma unroll
        for (int lf = 0; lf < 4; ++lf){
            int ol = om * 16 + hi * 4;
            int ll = lf * 16 + lo;
            ec[wv][ol + 0][ll] = acc[om][lf][0];
            ec[wv][ol + 1][ll] = acc[om][lf][1];
            ec[wv][ol + 2][ll] = acc[om][lf][2];
            ec[wv][ol + 3][ll] = acc[om][lf][3];
        }
    }
    __syncthreads();

    #pragma unroll
    for (int p = 0; p < 32; ++p){
        int orow = p * 4 + wv;           // 0..127
        float v = ec[orow >> 5][orow & 31][lane] + b_out[orow];
        out[((size_t)(b * 128 + orow)) * LL + l0 + lane] = v;
    }
}

// ---------------------------------------------------------------------------
extern "C" void kernel_launch(void* const* d_in, const int* in_sizes, int n_in,
                              void* d_out, int out_size, void* d_ws, size_t ws_size,
                              hipStream_t stream) {
    const float* x     = (const float*)d_in[0];
    const float* W_in  = (const float*)d_in[1];
    const float* b_in  = (const float*)d_in[2];
    const float* dw_w  = (const float*)d_in[3];
    const float* dw_b  = (const float*)d_in[4];
    const float* gamma = (const float*)d_in[5];
    const float* beta  = (const float*)d_in[6];
    const float* W_out = (const float*)d_in[7];
    const float* b_out = (const float*)d_in[8];
    float* out = (float*)d_out;

    const size_t NTOK = (size_t)BB * LL;          // 73728
    ushort_t* xT    = (ushort_t*)d_ws;            // (B,L,128) bf16
    ushort_t* U     = xT + NTOK * 128;            // (B,L,128) bf16
    ushort_t* V     = U  + NTOK * 128;            // (B,L,128) bf16
    ushort_t* WinB  = V  + NTOK * 128;            // 256x128 bf16
    ushort_t* WoutB = WinB + 256 * 128;           // 128x128 bf16
    ushort_t* ysum  = U;                          // alias (safe: per-token RAW only)

    k_prep<<<128, 256, 0, stream>>>(W_in, W_out, WinB, WoutB);

    dim3 gT(LL / 64, BB);
    k_xpose<<<gT, 256, 0, stream>>>(x, xT);

    dim3 gA(LL / 64, BB);
    k_gemmA<<<gA, 256, 0, stream>>>(xT, WinB, b_in, U, V);

    dim3 gB(3, HH, BB);
    k_mixer<<<gB, 256, 0, stream>>>(U, V, dw_w, dw_b, gamma, beta, ysum);

    dim3 gC(LL / 64, BB);
    k_gemmC<<<gC, 256, 0, stream>>>(ysum, WoutB, b_out, out);
}

// Round 3
// 128.537 us; speedup vs baseline: 2.3383x; 1.0128x over previous
//
#include <hip/hip_runtime.h>

#define BB 8
#define CC 128
#define HH 96
#define WW 96
#define LL 9216
#define EPSF 1e-5f

typedef __attribute__((ext_vector_type(8))) short short8;
typedef __attribute__((ext_vector_type(4))) float f32x4;
typedef __attribute__((ext_vector_type(4))) unsigned int uint32x4;
typedef unsigned short ushort_t;
typedef unsigned int uint32;

__device__ __forceinline__ float silu_f(float x){ return x / (1.0f + __expf(-x)); }
__device__ __forceinline__ ushort_t f2bf(float f){
    uint32 u = __float_as_uint(f);
    u += 0x7FFFu + ((u >> 16) & 1u);          // RNE
    return (ushort_t)(u >> 16);
}
__device__ __forceinline__ float bf2f(ushort_t h){ return __uint_as_float(((uint32)h) << 16); }
__device__ __forceinline__ uint32 pack2(float a, float b){
    return (uint32)f2bf(a) | ((uint32)f2bf(b) << 16);
}
// force a wave-uniform float into an SGPR
__device__ __forceinline__ float sload(float x){
    return __uint_as_float(__builtin_amdgcn_readfirstlane(__float_as_uint(x)));
}

// ---------------------------------------------------------------------------
// Convert W_in (256x128) and W_out (128x128) fp32 -> bf16. grid 128 x 256.
// ---------------------------------------------------------------------------
__global__ void k_prep(const float* __restrict__ Win, const float* __restrict__ Wout,
                       ushort_t* __restrict__ WinB, ushort_t* __restrict__ WoutB){
    int i = blockIdx.x * 256 + threadIdx.x;
    if (i < 256 * 128) WinB[i] = f2bf(Win[i]);
    if (i < 128 * 128) WoutB[i] = f2bf(Wout[i]);
}

// ---------------------------------------------------------------------------
// Transpose+convert x (B,128,L) fp32 -> xT (B,L,128) bf16. grid(144,B) x 256.
// ---------------------------------------------------------------------------
__global__ __launch_bounds__(256) void k_xpose(const float* __restrict__ x,
                                               ushort_t* __restrict__ xT){
    __shared__ float xt[128][65];
    const int b = blockIdx.y, l0 = blockIdx.x * 64, tid = threadIdx.x;
    const int col = tid & 63;
    #pragma unroll
    for (int k = 0; k < 32; ++k){
        int c = (tid >> 6) + k * 4;
        xt[c][col] = x[((size_t)(b * 128 + c)) * LL + l0 + col];
    }
    __syncthreads();
    const int lane = tid & 63;
    uint32* outbase = (uint32*)(xT + (size_t)b * LL * 128);
    #pragma unroll
    for (int p = 0; p < 16; ++p){
        int l = (tid >> 6) + p * 4;
        uint32 v = pack2(xt[2 * lane][l], xt[2 * lane + 1][l]);
        outbase[(size_t)(l0 + l) * 64 + lane] = v;
    }
}

// ---------------------------------------------------------------------------
// GEMM A: uv[o,l] = sum_c W_in[o,c] * x[c,l]; U = silu(uv[0:128]) bf16,
// V = uv[128:256] bf16, both token-major (B,L,128).
// ---------------------------------------------------------------------------
__global__ __launch_bounds__(256) void k_gemmA(const ushort_t* __restrict__ xT,
        const ushort_t* __restrict__ WinB, const float* __restrict__ b_in,
        ushort_t* __restrict__ U, ushort_t* __restrict__ V){
    __shared__ ushort_t eb[4][64][72];
    const int b = blockIdx.y, l0 = blockIdx.x * 64, tid = threadIdx.x;
    const int wv = tid >> 6, lane = tid & 63;
    const int lo = lane & 15, hi = lane >> 4;
    const int o0 = wv * 64;
    const ushort_t* xb = xT + (size_t)b * LL * 128;

    const f32x4 zero = {0.f, 0.f, 0.f, 0.f};
    f32x4 acc[4][4];
    #pragma unroll
    for (int om = 0; om < 4; ++om)
        #pragma unroll
        for (int lf = 0; lf < 4; ++lf) acc[om][lf] = zero;

    #pragma unroll
    for (int ks = 0; ks < 4; ++ks){
        short8 af[4], bfr[4];
        #pragma unroll
        for (int om = 0; om < 4; ++om)
            af[om] = *(const short8*)(WinB + (size_t)(o0 + om * 16 + lo) * 128 + ks * 32 + hi * 8);
        #pragma unroll
        for (int lf = 0; lf < 4; ++lf)
            bfr[lf] = *(const short8*)(xb + (size_t)(l0 + lf * 16 + lo) * 128 + ks * 32 + hi * 8);
        #pragma unroll
        for (int om = 0; om < 4; ++om)
            #pragma unroll
            for (int lf = 0; lf < 4; ++lf)
                acc[om][lf] = __builtin_amdgcn_mfma_f32_16x16x32_bf16(af[om], bfr[lf], acc[om][lf], 0, 0, 0);
    }

    const bool isU = (wv < 2);
    #pragma unroll
    for (int om = 0; om < 4; ++om){
        int ob = o0 + om * 16 + hi * 4;
        f32x4 bia = *(const f32x4*)(b_in + ob);
        #pragma unroll
        for (int lf = 0; lf < 4; ++lf){
            f32x4 v = acc[om][lf];
            float v0 = v[0] + bia[0], v1 = v[1] + bia[1];
            float v2 = v[2] + bia[2], v3 = v[3] + bia[3];
            if (isU){ v0 = silu_f(v0); v1 = silu_f(v1); v2 = silu_f(v2); v3 = silu_f(v3); }
            int ll = lf * 16 + lo;
            uint32* row = (uint32*)(&eb[wv][ll][0]);
            row[om * 8 + hi * 2    ] = pack2(v0, v1);
            row[om * 8 + hi * 2 + 1] = pack2(v2, v3);
        }
    }
    __syncthreads();

    uint32* Ub = (uint32*)(U + (size_t)b * LL * 128);
    uint32* Vb = (uint32*)(V + (size_t)b * LL * 128);
    const int wsrc = lane >> 5, jcol = lane & 31;
    #pragma unroll
    for (int p = 0; p < 16; ++p){
        int l = (tid >> 6) + p * 4;
        uint32 vu = ((uint32*)&eb[0 + wsrc][l][0])[jcol];
        uint32 vv = ((uint32*)&eb[2 + wsrc][l][0])[jcol];
        Ub[(size_t)(l0 + l) * 64 + lane] = vu;
        Vb[(size_t)(l0 + l) * 64 + lane] = vv;
    }
}

// ---------------------------------------------------------------------------
// Mixer: 4-direction depthwise conv + SiLU gate + LayerNorm, summed, *0.25.
// block 1024 = 16 waves; wave wv owns channels [8*wv, 8*wv+8); lane = token.
// Depthwise weights/bias are wave-uniform -> SGPRs (no loads in conv loop).
// gamma/beta factored out of the per-direction LN (linear) -> applied once.
// ysum aliases U (thread writes only its own (token,ch) chunk, after reads).
// grid(144, B) x 1024.
// ---------------------------------------------------------------------------
__global__ __launch_bounds__(1024) void k_mixer(const ushort_t* U,
        const ushort_t* __restrict__ V, const float* __restrict__ dw_w,
        const float* __restrict__ dw_b, const float* __restrict__ gamma,
        const float* __restrict__ beta, ushort_t* ysum){
    __shared__ float red[4][16][64];
    __shared__ float tot[4][64];
    const int b   = blockIdx.y;
    const int m0  = blockIdx.x * 64;
    const int tid = threadIdx.x;
    const int lane = tid & 63;
    const int wv  = __builtin_amdgcn_readfirstlane(tid >> 6);  // 0..15
    const int cb  = wv * 8;
    const int m   = m0 + lane;
    const int h   = m / WW, w = m % WW;

    // wave-uniform weights -> SGPRs
    float wgt[8][7], bias[8];
    #pragma unroll
    for (int i = 0; i < 8; ++i){
        bias[i] = sload(dw_b[cb + i]);
        #pragma unroll
        for (int j = 0; j < 7; ++j) wgt[i][j] = sload(dw_w[(cb + i) * 7 + j]);
    }

    int offH[7], offV[7];
    #pragma unroll
    for (int j = 0; j < 7; ++j){
        int d = j - 3;
        int mm = m + d;
        offH[j] = (mm >= 0 && mm < LL) ? mm : -1;
        int q = w * HH + h + d;                    // col-major flat pos + d
        offV[j] = (q >= 0 && q < LL) ? ((q % HH) * WW + q / HH) : -1;
    }

    const size_t base = (size_t)b * LL * 128;
    const ushort_t* Vb = V + base;

    float uf[8];
    {
        short8 u0 = *(const short8*)(U + base + (size_t)m * 128 + cb);
        #pragma unroll
        for (int i = 0; i < 8; ++i) uf[i] = bf2f((ushort_t)u0[i]);
    }

    float ysr[8];
    #pragma unroll
    for (int i = 0; i < 8; ++i) ysr[i] = 0.f;

    auto do_pair = [&](const int* off){
        short8 t[7];
        #pragma unroll
        for (int j = 0; j < 7; ++j){
            if (off[j] >= 0) t[j] = *(const short8*)(Vb + (size_t)off[j] * 128 + cb);
            else { short8 z = {0,0,0,0,0,0,0,0}; t[j] = z; }
        }
        float ya[8], yb[8];
        float sa = 0.f, qa = 0.f, sb = 0.f, qb = 0.f;
        #pragma unroll
        for (int i = 0; i < 8; ++i){
            float ca = bias[i], cbv = bias[i];
            #pragma unroll
            for (int j = 0; j < 7; ++j){
                float tv = bf2f((ushort_t)t[j][i]);
                ca  = fmaf(wgt[i][j],     tv, ca);   // forward kernel
                cbv = fmaf(wgt[i][6 - j], tv, cbv);  // flipped kernel
            }
            float va = uf[i] * silu_f(ca);
            float vb = uf[i] * silu_f(cbv);
            ya[i] = va; yb[i] = vb;
            sa += va; qa += va * va; sb += vb; qb += vb * vb;
        }
        red[0][wv][lane] = sa; red[1][wv][lane] = qa;
        red[2][wv][lane] = sb; red[3][wv][lane] = qb;
        __syncthreads();
        if (wv < 4){
            float s = 0.f;
            #pragma unroll
            for (int g = 0; g < 16; ++g) s += red[wv][g][lane];
            tot[wv][lane] = s;
        }
        __syncthreads();
        const float inv = 1.f / 128.f;
        float mua = tot[0][lane] * inv, vara = tot[1][lane] * inv - mua * mua;
        float mub = tot[2][lane] * inv, varb = tot[3][lane] * inv - mub * mub;
        float ra = rsqrtf(vara + EPSF), rb = rsqrtf(varb + EPSF);
        #pragma unroll
        for (int i = 0; i < 8; ++i)
            ysr[i] += (ya[i] - mua) * ra + (yb[i] - mub) * rb;
    };

    do_pair(offH);   // lr + rl
    do_pair(offV);   // tb + bt

    // apply gamma/beta once: sum_dirs LN = gamma * ysr + 4*beta; then * 0.25
    uint32 pk[4];
    #pragma unroll
    for (int i = 0; i < 4; ++i){
        float g0 = sload(gamma[cb + 2 * i]),     b0 = sload(beta[cb + 2 * i]);
        float g1 = sload(gamma[cb + 2 * i + 1]), b1 = sload(beta[cb + 2 * i + 1]);
        pk[i] = pack2(0.25f * g0 * ysr[2 * i] + b0,
                      0.25f * g1 * ysr[2 * i + 1] + b1);
    }
    uint32x4 s0 = {pk[0], pk[1], pk[2], pk[3]};
    *(uint32x4*)(ysum + base + (size_t)m * 128 + cb) = s0;
}

// ---------------------------------------------------------------------------
// GEMM C: out[o,l] = sum_c W_out[o,c] * ysum[l,c] + b_out[o], fp32 out
// channel-major (B,128,L). block 256 = 4 waves; wave owns 32-o chunk.
// ---------------------------------------------------------------------------
__global__ __launch_bounds__(256) void k_gemmC(const ushort_t* __restrict__ ysum,
        const ushort_t* __restrict__ WoutB, const float* __restrict__ b_out,
        float* __restrict__ out){
    __shared__ float ec[4][32][65];
    const int b = blockIdx.y, l0 = blockIdx.x * 64, tid = threadIdx.x;
    const int wv = tid >> 6, lane = tid & 63;
    const int lo = lane & 15, hi = lane >> 4;
    const int o0 = wv * 32;
    const ushort_t* yb = ysum + (size_t)b * LL * 128;

    const f32x4 zero = {0.f, 0.f, 0.f, 0.f};
    f32x4 acc[2][4];
    #pragma unroll
    for (int om = 0; om < 2; ++om)
        #pragma unroll
        for (int lf = 0; lf < 4; ++lf) acc[om][lf] = zero;

    #pragma unroll
    for (int ks = 0; ks < 4; ++ks){
        short8 af[2], bfr[4];
        #pragma unroll
        for (int om = 0; om < 2; ++om)
            af[om] = *(const short8*)(WoutB + (size_t)(o0 + om * 16 + lo) * 128 + ks * 32 + hi * 8);
        #pragma unroll
        for (int lf = 0; lf < 4; ++lf)
            bfr[lf] = *(const short8*)(yb + (size_t)(l0 + lf * 16 + lo) * 128 + ks * 32 + hi * 8);
        #pragma unroll
        for (int om = 0; om < 2; ++om)
            #pragma unroll
            for (int lf = 0; lf < 4; ++lf)
                acc[om][lf] = __builtin_amdgcn_mfma_f32_16x16x32_bf16(af[om], bfr[lf], acc[om][lf], 0, 0, 0);
    }

    #pragma unroll
    for (int om = 0; om < 2; ++om){
        #pragma unroll
        for (int lf = 0; lf < 4; ++lf){
            int ol = om * 16 + hi * 4;
            int ll = lf * 16 + lo;
            ec[wv][ol + 0][ll] = acc[om][lf][0];
            ec[wv][ol + 1][ll] = acc[om][lf][1];
            ec[wv][ol + 2][ll] = acc[om][lf][2];
            ec[wv][ol + 3][ll] = acc[om][lf][3];
        }
    }
    __syncthreads();

    #pragma unroll
    for (int p = 0; p < 32; ++p){
        int orow = p * 4 + wv;           // 0..127
        float v = ec[orow >> 5][orow & 31][lane] + b_out[orow];
        out[((size_t)(b * 128 + orow)) * LL + l0 + lane] = v;
    }
}

// ---------------------------------------------------------------------------
extern "C" void kernel_launch(void* const* d_in, const int* in_sizes, int n_in,
                              void* d_out, int out_size, void* d_ws, size_t ws_size,
                              hipStream_t stream) {
    const float* x     = (const float*)d_in[0];
    const float* W_in  = (const float*)d_in[1];
    const float* b_in  = (const float*)d_in[2];
    const float* dw_w  = (const float*)d_in[3];
    const float* dw_b  = (const float*)d_in[4];
    const float* gamma = (const float*)d_in[5];
    const float* beta  = (const float*)d_in[6];
    const float* W_out = (const float*)d_in[7];
    const float* b_out = (const float*)d_in[8];
    float* out = (float*)d_out;

    const size_t NTOK = (size_t)BB * LL;          // 73728
    ushort_t* xT    = (ushort_t*)d_ws;            // (B,L,128) bf16
    ushort_t* U     = xT + NTOK * 128;            // (B,L,128) bf16
    ushort_t* V     = U  + NTOK * 128;            // (B,L,128) bf16
    ushort_t* WinB  = V  + NTOK * 128;            // 256x128 bf16
    ushort_t* WoutB = WinB + 256 * 128;           // 128x128 bf16
    ushort_t* ysum  = U;                          // alias (safe: per-token RAW only)

    k_prep<<<128, 256, 0, stream>>>(W_in, W_out, WinB, WoutB);

    dim3 gT(LL / 64, BB);
    k_xpose<<<gT, 256, 0, stream>>>(x, xT);

    dim3 gA(LL / 64, BB);
    k_gemmA<<<gA, 256, 0, stream>>>(xT, WinB, b_in, U, V);

    dim3 gB(LL / 64, BB);
    k_mixer<<<gB, 1024, 0, stream>>>(U, V, dw_w, dw_b, gamma, beta, ysum);

    dim3 gC(LL / 64, BB);
    k_gemmC<<<gC, 256, 0, stream>>>(ysum, WoutB, b_out, out);
}

// Round 4
// 118.105 us; speedup vs baseline: 2.5448x; 1.0883x over previous
//
#include <hip/hip_runtime.h>

#define BB 8
#define CC 128
#define HH 96
#define WW 96
#define LL 9216
#define EPSF 1e-5f

typedef __attribute__((ext_vector_type(8))) short short8;
typedef __attribute__((ext_vector_type(4))) float f32x4;
typedef __attribute__((ext_vector_type(4))) unsigned int uint32x4;
typedef unsigned short ushort_t;
typedef unsigned int uint32;

__device__ __forceinline__ float silu_f(float x){ return x / (1.0f + __expf(-x)); }
__device__ __forceinline__ ushort_t f2bf(float f){
    uint32 u = __float_as_uint(f);
    u += 0x7FFFu + ((u >> 16) & 1u);          // RNE
    return (ushort_t)(u >> 16);
}
__device__ __forceinline__ float bf2f(ushort_t h){ return __uint_as_float(((uint32)h) << 16); }
__device__ __forceinline__ uint32 pack2(float a, float b){
    return (uint32)f2bf(a) | ((uint32)f2bf(b) << 16);
}
// force a wave-uniform float into an SGPR
__device__ __forceinline__ float sload(float x){
    return __uint_as_float(__builtin_amdgcn_readfirstlane(__float_as_uint(x)));
}

// ---------------------------------------------------------------------------
// Fused: transpose+convert x (B,128,L) fp32 -> xT (B,L,128) bf16, and
// (blockIdx.x==144 slice) convert W_in/W_out fp32 -> bf16.
// grid(145, B) x 256.
// ---------------------------------------------------------------------------
__global__ __launch_bounds__(256) void k_prep_xpose(const float* __restrict__ x,
        const float* __restrict__ Win, const float* __restrict__ Wout,
        ushort_t* __restrict__ xT, ushort_t* __restrict__ WinB,
        ushort_t* __restrict__ WoutB){
    if (blockIdx.x == 144){
        int base = blockIdx.y * 256 + threadIdx.x;      // 0..2047
        for (int i = base; i < 256 * 128; i += 2048) WinB[i] = f2bf(Win[i]);
        for (int i = base; i < 128 * 128; i += 2048) WoutB[i] = f2bf(Wout[i]);
        return;
    }
    __shared__ float xt[128][65];
    const int b = blockIdx.y, l0 = blockIdx.x * 64, tid = threadIdx.x;
    const int col = tid & 63;
    #pragma unroll
    for (int k = 0; k < 32; ++k){
        int c = (tid >> 6) + k * 4;
        xt[c][col] = x[((size_t)(b * 128 + c)) * LL + l0 + col];
    }
    __syncthreads();
    const int lane = tid & 63;
    uint32* outbase = (uint32*)(xT + (size_t)b * LL * 128);
    #pragma unroll
    for (int p = 0; p < 16; ++p){
        int l = (tid >> 6) + p * 4;
        uint32 v = pack2(xt[2 * lane][l], xt[2 * lane + 1][l]);
        outbase[(size_t)(l0 + l) * 64 + lane] = v;
    }
}

// ---------------------------------------------------------------------------
// GEMM A: uv[o,l] = sum_c W_in[o,c] * x[c,l]; U = silu(uv[0:128]) bf16,
// V = uv[128:256] bf16, both token-major (B,L,128).
// ---------------------------------------------------------------------------
__global__ __launch_bounds__(256) void k_gemmA(const ushort_t* __restrict__ xT,
        const ushort_t* __restrict__ WinB, const float* __restrict__ b_in,
        ushort_t* __restrict__ U, ushort_t* __restrict__ V){
    __shared__ ushort_t eb[4][64][72];
    const int b = blockIdx.y, l0 = blockIdx.x * 64, tid = threadIdx.x;
    const int wv = tid >> 6, lane = tid & 63;
    const int lo = lane & 15, hi = lane >> 4;
    const int o0 = wv * 64;
    const ushort_t* xb = xT + (size_t)b * LL * 128;

    const f32x4 zero = {0.f, 0.f, 0.f, 0.f};
    f32x4 acc[4][4];
    #pragma unroll
    for (int om = 0; om < 4; ++om)
        #pragma unroll
        for (int lf = 0; lf < 4; ++lf) acc[om][lf] = zero;

    #pragma unroll
    for (int ks = 0; ks < 4; ++ks){
        short8 af[4], bfr[4];
        #pragma unroll
        for (int om = 0; om < 4; ++om)
            af[om] = *(const short8*)(WinB + (size_t)(o0 + om * 16 + lo) * 128 + ks * 32 + hi * 8);
        #pragma unroll
        for (int lf = 0; lf < 4; ++lf)
            bfr[lf] = *(const short8*)(xb + (size_t)(l0 + lf * 16 + lo) * 128 + ks * 32 + hi * 8);
        #pragma unroll
        for (int om = 0; om < 4; ++om)
            #pragma unroll
            for (int lf = 0; lf < 4; ++lf)
                acc[om][lf] = __builtin_amdgcn_mfma_f32_16x16x32_bf16(af[om], bfr[lf], acc[om][lf], 0, 0, 0);
    }

    const bool isU = (wv < 2);
    #pragma unroll
    for (int om = 0; om < 4; ++om){
        int ob = o0 + om * 16 + hi * 4;
        f32x4 bia = *(const f32x4*)(b_in + ob);
        #pragma unroll
        for (int lf = 0; lf < 4; ++lf){
            f32x4 v = acc[om][lf];
            float v0 = v[0] + bia[0], v1 = v[1] + bia[1];
            float v2 = v[2] + bia[2], v3 = v[3] + bia[3];
            if (isU){ v0 = silu_f(v0); v1 = silu_f(v1); v2 = silu_f(v2); v3 = silu_f(v3); }
            int ll = lf * 16 + lo;
            uint32* row = (uint32*)(&eb[wv][ll][0]);
            row[om * 8 + hi * 2    ] = pack2(v0, v1);
            row[om * 8 + hi * 2 + 1] = pack2(v2, v3);
        }
    }
    __syncthreads();

    uint32* Ub = (uint32*)(U + (size_t)b * LL * 128);
    uint32* Vb = (uint32*)(V + (size_t)b * LL * 128);
    const int wsrc = lane >> 5, jcol = lane & 31;
    #pragma unroll
    for (int p = 0; p < 16; ++p){
        int l = (tid >> 6) + p * 4;
        uint32 vu = ((uint32*)&eb[0 + wsrc][l][0])[jcol];
        uint32 vv = ((uint32*)&eb[2 + wsrc][l][0])[jcol];
        Ub[(size_t)(l0 + l) * 64 + lane] = vu;
        Vb[(size_t)(l0 + l) * 64 + lane] = vv;
    }
}

// ---------------------------------------------------------------------------
// Fused mixer + output GEMM.
// Phase 1 (mixer): 4-direction depthwise conv + SiLU gate + LN, summed, *0.25.
//   block 1024 = 16 waves; wave wv owns channels [8*wv,8*wv+8); lane = token.
//   Result packed bf16 into LDS ytile[64][136].
// Phase 2 (GEMM): out[o, l] = sum_c W_out[o,c]*ytile[l][c] + b_out[o].
//   wave wv: o-frag = wv>>1 (16 o), l-frags {2*(wv&1), 2*(wv&1)+1} (32 l).
// grid(144, B) x 1024.
// ---------------------------------------------------------------------------
__global__ __launch_bounds__(1024) void k_mixout(const ushort_t* __restrict__ U,
        const ushort_t* __restrict__ V, const float* __restrict__ dw_w,
        const float* __restrict__ dw_b, const float* __restrict__ gamma,
        const float* __restrict__ beta, const ushort_t* __restrict__ WoutB,
        const float* __restrict__ b_out, float* __restrict__ out){
    __shared__ float red[4][16][64];
    __shared__ float tot[4][64];
    __shared__ ushort_t ytile[64][136];
    const int b   = blockIdx.y;
    const int m0  = blockIdx.x * 64;
    const int tid = threadIdx.x;
    const int lane = tid & 63;
    const int lo = lane & 15, hi = lane >> 4;
    const int wv  = __builtin_amdgcn_readfirstlane(tid >> 6);  // 0..15
    const int cb  = wv * 8;
    const int m   = m0 + lane;
    const int h   = m / WW, w = m % WW;

    // wave-uniform conv weights -> SGPRs
    float wgt[8][7], bias[8];
    #pragma unroll
    for (int i = 0; i < 8; ++i){
        bias[i] = sload(dw_b[cb + i]);
        #pragma unroll
        for (int j = 0; j < 7; ++j) wgt[i][j] = sload(dw_w[(cb + i) * 7 + j]);
    }

    int offH[7], offV[7];
    #pragma unroll
    for (int j = 0; j < 7; ++j){
        int d = j - 3;
        int mm = m + d;
        offH[j] = (mm >= 0 && mm < LL) ? mm : -1;
        int q = w * HH + h + d;                    // col-major flat pos + d
        offV[j] = (q >= 0 && q < LL) ? ((q % HH) * WW + q / HH) : -1;
    }

    const size_t base = (size_t)b * LL * 128;
    const ushort_t* Vb = V + base;

    float uf[8];
    {
        short8 u0 = *(const short8*)(U + base + (size_t)m * 128 + cb);
        #pragma unroll
        for (int i = 0; i < 8; ++i) uf[i] = bf2f((ushort_t)u0[i]);
    }

    float ysr[8];
    #pragma unroll
    for (int i = 0; i < 8; ++i) ysr[i] = 0.f;

    auto do_pair = [&](const int* off){
        short8 t[7];
        #pragma unroll
        for (int j = 0; j < 7; ++j){
            if (off[j] >= 0) t[j] = *(const short8*)(Vb + (size_t)off[j] * 128 + cb);
            else { short8 z = {0,0,0,0,0,0,0,0}; t[j] = z; }
        }
        float ya[8], yb[8];
        float sa = 0.f, qa = 0.f, sb = 0.f, qb = 0.f;
        #pragma unroll
        for (int i = 0; i < 8; ++i){
            float ca = bias[i], cbv = bias[i];
            #pragma unroll
            for (int j = 0; j < 7; ++j){
                float tv = bf2f((ushort_t)t[j][i]);
                ca  = fmaf(wgt[i][j],     tv, ca);   // forward kernel
                cbv = fmaf(wgt[i][6 - j], tv, cbv);  // flipped kernel
            }
            float va = uf[i] * silu_f(ca);
            float vb = uf[i] * silu_f(cbv);
            ya[i] = va; yb[i] = vb;
            sa += va; qa += va * va; sb += vb; qb += vb * vb;
        }
        red[0][wv][lane] = sa; red[1][wv][lane] = qa;
        red[2][wv][lane] = sb; red[3][wv][lane] = qb;
        __syncthreads();
        if (wv < 4){
            float s = 0.f;
            #pragma unroll
            for (int g = 0; g < 16; ++g) s += red[wv][g][lane];
            tot[wv][lane] = s;
        }
        __syncthreads();
        const float inv = 1.f / 128.f;
        float mua = tot[0][lane] * inv, vara = tot[1][lane] * inv - mua * mua;
        float mub = tot[2][lane] * inv, varb = tot[3][lane] * inv - mub * mub;
        float ra = rsqrtf(vara + EPSF), rb = rsqrtf(varb + EPSF);
        #pragma unroll
        for (int i = 0; i < 8; ++i)
            ysr[i] += (ya[i] - mua) * ra + (yb[i] - mub) * rb;
        __syncthreads();    // red/tot reused by next pair
    };

    do_pair(offH);   // lr + rl
    do_pair(offV);   // tb + bt

    // sum_dirs LN = gamma * ysr + 4*beta; *0.25 -> pack bf16 into ytile
    uint32 pk[4];
    #pragma unroll
    for (int i = 0; i < 4; ++i){
        float g0 = sload(gamma[cb + 2 * i]),     b0 = sload(beta[cb + 2 * i]);
        float g1 = sload(gamma[cb + 2 * i + 1]), b1 = sload(beta[cb + 2 * i + 1]);
        pk[i] = pack2(0.25f * g0 * ysr[2 * i] + b0,
                      0.25f * g1 * ysr[2 * i + 1] + b1);
    }
    uint32x4 s0 = {pk[0], pk[1], pk[2], pk[3]};
    *(uint32x4*)(&ytile[lane][cb]) = s0;
    __syncthreads();

    // ---- Phase 2: output GEMM from LDS ytile -------------------------------
    const int ow = wv >> 1;              // 0..7  -> o-range [16*ow, 16*ow+16)
    const int lp = (wv & 1) * 2;         // l-frag base: 0 or 2
    const f32x4 zero = {0.f, 0.f, 0.f, 0.f};
    f32x4 acc2[2] = {zero, zero};
    #pragma unroll
    for (int ks = 0; ks < 4; ++ks){
        short8 af = *(const short8*)(WoutB + (size_t)(ow * 16 + lo) * 128 + ks * 32 + hi * 8);
        #pragma unroll
        for (int t2 = 0; t2 < 2; ++t2){
            short8 bfr = *(const short8*)(&ytile[(lp + t2) * 16 + lo][ks * 32 + hi * 8]);
            acc2[t2] = __builtin_amdgcn_mfma_f32_16x16x32_bf16(af, bfr, acc2[t2], 0, 0, 0);
        }
    }
    f32x4 bia = *(const f32x4*)(b_out + ow * 16 + hi * 4);
    #pragma unroll
    for (int t2 = 0; t2 < 2; ++t2){
        int l = m0 + (lp + t2) * 16 + lo;
        #pragma unroll
        for (int r = 0; r < 4; ++r){
            int o = ow * 16 + hi * 4 + r;
            out[((size_t)(b * 128 + o)) * LL + l] = acc2[t2][r] + bia[r];
        }
    }
}

// ---------------------------------------------------------------------------
extern "C" void kernel_launch(void* const* d_in, const int* in_sizes, int n_in,
                              void* d_out, int out_size, void* d_ws, size_t ws_size,
                              hipStream_t stream) {
    const float* x     = (const float*)d_in[0];
    const float* W_in  = (const float*)d_in[1];
    const float* b_in  = (const float*)d_in[2];
    const float* dw_w  = (const float*)d_in[3];
    const float* dw_b  = (const float*)d_in[4];
    const float* gamma = (const float*)d_in[5];
    const float* beta  = (const float*)d_in[6];
    const float* W_out = (const float*)d_in[7];
    const float* b_out = (const float*)d_in[8];
    float* out = (float*)d_out;

    const size_t NTOK = (size_t)BB * LL;          // 73728
    ushort_t* xT    = (ushort_t*)d_ws;            // (B,L,128) bf16
    ushort_t* U     = xT + NTOK * 128;            // (B,L,128) bf16
    ushort_t* V     = U  + NTOK * 128;            // (B,L,128) bf16
    ushort_t* WinB  = V  + NTOK * 128;            // 256x128 bf16
    ushort_t* WoutB = WinB + 256 * 128;           // 128x128 bf16

    dim3 gT(145, BB);
    k_prep_xpose<<<gT, 256, 0, stream>>>(x, W_in, W_out, xT, WinB, WoutB);

    dim3 gA(LL / 64, BB);
    k_gemmA<<<gA, 256, 0, stream>>>(xT, WinB, b_in, U, V);

    dim3 gM(LL / 64, BB);
    k_mixout<<<gM, 1024, 0, stream>>>(U, V, dw_w, dw_b, gamma, beta,
                                      WoutB, b_out, out);
}

// Round 5
// 117.913 us; speedup vs baseline: 2.5490x; 1.0016x over previous
//
#include <hip/hip_runtime.h>

#define BB 8
#define CC 128
#define HH 96
#define WW 96
#define LL 9216
#define EPSF 1e-5f
#define SLOTS 454   // 70 H-window + 6*64 V-rows

typedef __attribute__((ext_vector_type(8))) short short8;
typedef __attribute__((ext_vector_type(4))) float f32x4;
typedef __attribute__((ext_vector_type(4))) unsigned int uint32x4;
typedef unsigned short ushort_t;
typedef unsigned int uint32;

__device__ __forceinline__ float silu_f(float x){ return x / (1.0f + __expf(-x)); }
__device__ __forceinline__ ushort_t f2bf(float f){
    uint32 u = __float_as_uint(f);
    u += 0x7FFFu + ((u >> 16) & 1u);          // RNE
    return (ushort_t)(u >> 16);
}
__device__ __forceinline__ float bf2f(ushort_t h){ return __uint_as_float(((uint32)h) << 16); }
__device__ __forceinline__ uint32 pack2(float a, float b){
    return (uint32)f2bf(a) | ((uint32)f2bf(b) << 16);
}
__device__ __forceinline__ float sload(float x){
    return __uint_as_float(__builtin_amdgcn_readfirstlane(__float_as_uint(x)));
}

// ---------------------------------------------------------------------------
// Convert W_in (256x128) and W_out (128x128) fp32 -> bf16. grid 128 x 256.
// ---------------------------------------------------------------------------
__global__ void k_prep(const float* __restrict__ Win, const float* __restrict__ Wout,
                       ushort_t* __restrict__ WinB, ushort_t* __restrict__ WoutB){
    int i = blockIdx.x * 256 + threadIdx.x;
    if (i < 256 * 128) WinB[i] = f2bf(Win[i]);
    if (i < 128 * 128) WoutB[i] = f2bf(Wout[i]);
}

// ---------------------------------------------------------------------------
// GEMM A (fused transpose): reads x (B,128,L) fp32 directly.
// Stage fp32 tile -> pack bf16 token-major into swizzled LDS -> MFMA ->
// U = silu(uv[0:128]), V = uv[128:256], token-major bf16 (B,L,128).
// grid(144,B) x 256.
// ---------------------------------------------------------------------------
__global__ __launch_bounds__(256) void k_gemmA(const float* __restrict__ x,
        const ushort_t* __restrict__ WinB, const float* __restrict__ b_in,
        ushort_t* __restrict__ U, ushort_t* __restrict__ V){
    __shared__ __align__(16) char unia[36864];          // xt fp32 | eb (union)
    float (*xt)[65] = (float(*)[65])unia;               // [128][65]
    ushort_t (*eb)[64][72] = (ushort_t(*)[64][72])unia; // [4][64][72]
    __shared__ __align__(16) ushort_t xtile[64 * 128];  // swizzled token-major

    const int b = blockIdx.y, l0 = blockIdx.x * 64, tid = threadIdx.x;
    const int wv = tid >> 6, lane = tid & 63;
    const int lo = lane & 15, hi = lane >> 4;
    const int o0 = wv * 64;

    // stage x tile fp32 (coalesced 256B rows)
    #pragma unroll
    for (int k = 0; k < 32; ++k){
        int c = (tid >> 6) + k * 4;
        xt[c][lane] = x[((size_t)(b * 128 + c)) * LL + l0 + lane];
    }
    __syncthreads();
    // pack bf16 token-major, XOR-swizzled
    #pragma unroll
    for (int p = 0; p < 16; ++p){
        int l = (tid >> 6) + p * 4;
        uint32 v = pack2(xt[2 * lane][l], xt[2 * lane + 1][l]);
        *(uint32*)((char*)xtile + l * 256 + ((lane * 4) ^ ((l & 7) << 4))) = v;
    }
    __syncthreads();

    const f32x4 zero = {0.f, 0.f, 0.f, 0.f};
    f32x4 acc[4][4];
    #pragma unroll
    for (int om = 0; om < 4; ++om)
        #pragma unroll
        for (int lf = 0; lf < 4; ++lf) acc[om][lf] = zero;

    #pragma unroll
    for (int ks = 0; ks < 4; ++ks){
        short8 af[4], bfr[4];
        #pragma unroll
        for (int om = 0; om < 4; ++om)
            af[om] = *(const short8*)(WinB + (size_t)(o0 + om * 16 + lo) * 128 + ks * 32 + hi * 8);
        #pragma unroll
        for (int lf = 0; lf < 4; ++lf){
            int tok = lf * 16 + lo;
            bfr[lf] = *(const short8*)((char*)xtile + tok * 256 +
                        ((ks * 64 + hi * 16) ^ ((tok & 7) << 4)));
        }
        #pragma unroll
        for (int om = 0; om < 4; ++om)
            #pragma unroll
            for (int lf = 0; lf < 4; ++lf)
                acc[om][lf] = __builtin_amdgcn_mfma_f32_16x16x32_bf16(af[om], bfr[lf], acc[om][lf], 0, 0, 0);
    }

    const bool isU = (wv < 2);
    #pragma unroll
    for (int om = 0; om < 4; ++om){
        int ob = o0 + om * 16 + hi * 4;
        f32x4 bia = *(const f32x4*)(b_in + ob);
        #pragma unroll
        for (int lf = 0; lf < 4; ++lf){
            f32x4 v = acc[om][lf];
            float v0 = v[0] + bia[0], v1 = v[1] + bia[1];
            float v2 = v[2] + bia[2], v3 = v[3] + bia[3];
            if (isU){ v0 = silu_f(v0); v1 = silu_f(v1); v2 = silu_f(v2); v3 = silu_f(v3); }
            int ll = lf * 16 + lo;
            uint32* row = (uint32*)(&eb[wv][ll][0]);
            row[om * 8 + hi * 2    ] = pack2(v0, v1);
            row[om * 8 + hi * 2 + 1] = pack2(v2, v3);
        }
    }
    __syncthreads();

    uint32* Ub = (uint32*)(U + (size_t)b * LL * 128);
    uint32* Vb = (uint32*)(V + (size_t)b * LL * 128);
    const int wsrc = lane >> 5, jcol = lane & 31;
    #pragma unroll
    for (int p = 0; p < 16; ++p){
        int l = (tid >> 6) + p * 4;
        uint32 vu = ((uint32*)&eb[0 + wsrc][l][0])[jcol];
        uint32 vv = ((uint32*)&eb[2 + wsrc][l][0])[jcol];
        Ub[(size_t)(l0 + l) * 64 + lane] = vu;
        Vb[(size_t)(l0 + l) * 64 + lane] = vv;
    }
}

// ---------------------------------------------------------------------------
// Fused mixer + output GEMM, LDS-staged taps.
// block 1024 = 16 waves; wave wv owns channels [8wv, 8wv+8); lane = token.
// Stage V rows for flat tokens [m0-3, m0+66] (H-window, slots 0..69) and
// [m0+96*dd, m0+96*dd+63] for dd in {-3..3}\{0} (slots 70+r*64+..), XOR-swz.
// Vertical tap (h+dd, w) == flat m+96*dd (exact, even for row-crossing tiles);
// col-major wrap rows handled by block-uniform global fallback.
// grid(144, B) x 1024.
// ---------------------------------------------------------------------------
__global__ __launch_bounds__(1024) void k_mixout(const ushort_t* __restrict__ U,
        const ushort_t* __restrict__ V, const float* __restrict__ dw_w,
        const float* __restrict__ dw_b, const float* __restrict__ gamma,
        const float* __restrict__ beta, const ushort_t* __restrict__ WoutB,
        const float* __restrict__ b_out, float* __restrict__ out){
    __shared__ __align__(16) ushort_t Vs[SLOTS * 128];   // 116224 B swizzled
    __shared__ __align__(16) char uni[33792];            // red|tot|ytile, ybuf
    float* red = (float*)uni;                            // [4][16][64]
    float* tot = (float*)(uni + 16384);                  // [4][64]
    ushort_t* ytile = (ushort_t*)(uni + 17408);          // [64][128] swizzled
    float* ybuf = (float*)uni;                           // [128][65]

    const int b   = blockIdx.y;
    const int m0  = blockIdx.x * 64;
    const int tid = threadIdx.x;
    const int lane = tid & 63;
    const int lo = lane & 15, hi = lane >> 4;
    const int wv  = __builtin_amdgcn_readfirstlane(tid >> 6);  // 0..15
    const int cb  = wv * 8;
    const int m   = m0 + lane;
    const int h_l = m / WW, w_l = m - h_l * WW;

    const size_t base = (size_t)b * LL * 128;
    const ushort_t* Vb = V + base;

    // early U load (strided once; overlaps staging)
    short8 u8 = *(const short8*)(U + base + (size_t)m * 128 + cb);

    // wave-uniform conv weights -> SGPRs
    float wgt[8][7], bias[8];
    #pragma unroll
    for (int i = 0; i < 8; ++i){
        bias[i] = sload(dw_b[cb + i]);
        #pragma unroll
        for (int j = 0; j < 7; ++j) wgt[i][j] = sload(dw_w[(cb + i) * 7 + j]);
    }

    // ---- stage Vs (coalesced) ---------------------------------------------
    #pragma unroll
    for (int k = 0; k < 8; ++k){
        int q = tid + k * 1024;
        if (q < SLOTS * 16){
            int s = q >> 4, c16 = q & 15;
            int g;
            if (s < 70) g = m0 - 3 + s;
            else {
                int j = s - 70; int r = j >> 6; int wwj = j & 63;
                int dd = (r < 3) ? (r - 3) : (r - 2);
                g = m0 + 96 * dd + wwj;
            }
            uint32x4 val = {0u, 0u, 0u, 0u};
            if (g >= 0 && g < LL)
                val = *(const uint32x4*)(Vb + (size_t)g * 128 + c16 * 8);
            *(uint32x4*)((char*)Vs + s * 256 + ((c16 * 16) ^ ((s & 7) << 4))) = val;
        }
    }
    __syncthreads();

    float uf[8];
    #pragma unroll
    for (int i = 0; i < 8; ++i) uf[i] = bf2f((ushort_t)u8[i]);

    float ysr[8];
    #pragma unroll
    for (int i = 0; i < 8; ++i) ysr[i] = 0.f;

    auto ldtap = [&](int s)->short8 {
        return *(const short8*)((const char*)Vs + s * 256 + ((cb * 2) ^ ((s & 7) << 4)));
    };

    const float inv = 1.f / 128.f;
    auto conv_ln = [&](const short8* t){
        float ya[8], yb[8];
        float sa = 0.f, qa = 0.f, sb = 0.f, qb = 0.f;
        #pragma unroll
        for (int i = 0; i < 8; ++i){
            float ca = bias[i], cbv = bias[i];
            #pragma unroll
            for (int j = 0; j < 7; ++j){
                float tvv = bf2f((ushort_t)t[j][i]);
                ca  = fmaf(wgt[i][j],     tvv, ca);    // forward kernel
                cbv = fmaf(wgt[i][6 - j], tvv, cbv);   // flipped (reversed dir)
            }
            float va = uf[i] * silu_f(ca);
            float vb = uf[i] * silu_f(cbv);
            ya[i] = va; yb[i] = vb;
            sa += va; qa += va * va; sb += vb; qb += vb * vb;
        }
        red[(0 * 16 + wv) * 64 + lane] = sa;
        red[(1 * 16 + wv) * 64 + lane] = qa;
        red[(2 * 16 + wv) * 64 + lane] = sb;
        red[(3 * 16 + wv) * 64 + lane] = qb;
        __syncthreads();
        if (tid < 256){
            int st = tid >> 6, ln2 = tid & 63;
            float s = 0.f;
            #pragma unroll
            for (int g = 0; g < 16; ++g) s += red[(st * 16 + g) * 64 + ln2];
            tot[st * 64 + ln2] = s;
        }
        __syncthreads();
        float mua = tot[0 * 64 + lane] * inv, vara = tot[1 * 64 + lane] * inv - mua * mua;
        float mub = tot[2 * 64 + lane] * inv, varb = tot[3 * 64 + lane] * inv - mub * mub;
        float ra = rsqrtf(vara + EPSF), rb = rsqrtf(varb + EPSF);
        #pragma unroll
        for (int i = 0; i < 8; ++i)
            ysr[i] += (ya[i] - mua) * ra + (yb[i] - mub) * rb;
    };

    // ---- pair 1: lr + rl (flat H taps, always staged) ----------------------
    {
        short8 t[7];
        #pragma unroll
        for (int jj = 0; jj < 7; ++jj) t[jj] = ldtap(lane + jj);
        conv_ln(t);
    }
    // ---- pair 2: tb + bt (vertical taps) -----------------------------------
    {
        short8 t[7];
        t[3] = ldtap(lane + 3);     // dd = 0 tap from H-window
        #pragma unroll
        for (int r = 0; r < 6; ++r){
            const int dd = (r < 3) ? (r - 3) : (r - 2);
            const int jj = dd + 3;
            if (m0 + 96 * dd >= 0 && m0 + 63 + 96 * dd < LL){
                t[jj] = ldtap(70 + r * 64 + lane);
            } else {
                short8 z = {0,0,0,0,0,0,0,0};
                t[jj] = z;
                int q2 = w_l * HH + h_l + dd;     // col-major flat + d
                if (q2 >= 0 && q2 < LL){
                    int t2 = (q2 % HH) * WW + q2 / HH;
                    t[jj] = *(const short8*)(Vb + (size_t)t2 * 128 + cb);
                }
            }
        }
        conv_ln(t);
    }

    // ---- LN affine + pack to swizzled ytile --------------------------------
    uint32 pk[4];
    #pragma unroll
    for (int i = 0; i < 4; ++i){
        float g0 = sload(gamma[cb + 2 * i]),     b0 = sload(beta[cb + 2 * i]);
        float g1 = sload(gamma[cb + 2 * i + 1]), b1 = sload(beta[cb + 2 * i + 1]);
        pk[i] = pack2(0.25f * g0 * ysr[2 * i] + b0,
                      0.25f * g1 * ysr[2 * i + 1] + b1);
    }
    uint32x4 s0 = {pk[0], pk[1], pk[2], pk[3]};
    *(uint32x4*)((char*)ytile + lane * 256 + ((wv * 16) ^ ((lane & 7) << 4))) = s0;
    __syncthreads();

    // ---- Phase 2: output GEMM from ytile -----------------------------------
    const int ow = wv >> 1;              // o-range [16*ow, 16*ow+16)
    const int lp = (wv & 1) * 2;         // l-frag base
    const f32x4 zero = {0.f, 0.f, 0.f, 0.f};
    f32x4 acc2[2] = {zero, zero};
    #pragma unroll
    for (int ks = 0; ks < 4; ++ks){
        short8 af = *(const short8*)(WoutB + (size_t)(ow * 16 + lo) * 128 + ks * 32 + hi * 8);
        #pragma unroll
        for (int t2 = 0; t2 < 2; ++t2){
            int tok = (lp + t2) * 16 + lo;
            short8 bfr = *(const short8*)((char*)ytile + tok * 256 +
                            ((ks * 64 + hi * 16) ^ ((tok & 7) << 4)));
            acc2[t2] = __builtin_amdgcn_mfma_f32_16x16x32_bf16(af, bfr, acc2[t2], 0, 0, 0);
        }
    }
    __syncthreads();   // ytile reads done; ybuf overlays uni

    #pragma unroll
    for (int t2 = 0; t2 < 2; ++t2){
        int tok = (lp + t2) * 16 + lo;
        #pragma unroll
        for (int r = 0; r < 4; ++r){
            int o = ow * 16 + hi * 4 + r;
            ybuf[o * 65 + tok] = acc2[t2][r];
        }
    }
    __syncthreads();

    // coalesced fp32 stores (+bias)
    #pragma unroll
    for (int it = 0; it < 8; ++it){
        int o = (tid >> 6) + it * 16;
        float v = ybuf[o * 65 + lane] + b_out[o];
        out[((size_t)(b * 128 + o)) * LL + m0 + lane] = v;
    }
}

// ---------------------------------------------------------------------------
extern "C" void kernel_launch(void* const* d_in, const int* in_sizes, int n_in,
                              void* d_out, int out_size, void* d_ws, size_t ws_size,
                              hipStream_t stream) {
    const float* x     = (const float*)d_in[0];
    const float* W_in  = (const float*)d_in[1];
    const float* b_in  = (const float*)d_in[2];
    const float* dw_w  = (const float*)d_in[3];
    const float* dw_b  = (const float*)d_in[4];
    const float* gamma = (const float*)d_in[5];
    const float* beta  = (const float*)d_in[6];
    const float* W_out = (const float*)d_in[7];
    const float* b_out = (const float*)d_in[8];
    float* out = (float*)d_out;

    const size_t NTOK = (size_t)BB * LL;          // 73728
    ushort_t* U     = (ushort_t*)d_ws;            // (B,L,128) bf16
    ushort_t* V     = U + NTOK * 128;             // (B,L,128) bf16
    ushort_t* WinB  = V + NTOK * 128;             // 256x128 bf16
    ushort_t* WoutB = WinB + 256 * 128;           // 128x128 bf16

    k_prep<<<128, 256, 0, stream>>>(W_in, W_out, WinB, WoutB);

    dim3 gA(LL / 64, BB);
    k_gemmA<<<gA, 256, 0, stream>>>(x, WinB, b_in, U, V);

    dim3 gM(LL / 64, BB);
    k_mixout<<<gM, 1024, 0, stream>>>(U, V, dw_w, dw_b, gamma, beta,
                                      WoutB, b_out, out);
}